// Round 2
// baseline (237.525 us; speedup 1.0000x reference)
//
#include <hip/hip_runtime.h>
#include <hip/hip_cooperative_groups.h>

namespace cg = cooperative_groups;

// Problem constants (from reference)
#define NUM_DAYS    4096
#define NUM_ATTR    512
#define MB_WIN      128
#define HID         500
#define NUM_BATCHES (NUM_DAYS - MB_WIN)        // 3968
#define NUM_Y       (NUM_BATCHES + MB_WIN - 1) // 4095 distinct day indices
#define OUT_ELEMS   (NUM_BATCHES * MB_WIN)     // 507904

// ---------------------------------------------------------------------------
// Single cooperative kernel, three phases separated by grid.sync():
//   A: fold MLP:   v[a] = W1[a,:]·W2  (a<512);  c = b1·W2 + b2
//   B: day dots:   y[d] = x[d,:]·v + c          (d<4095)
//   C: replicate:  out[w*128 .. w*128+127] = y[w .. w+127] (coalesced float4)
// Grid: 1024 blocks x 256 threads = 4096 waves, co-resident (4 blocks/CU).
// ---------------------------------------------------------------------------
__global__ __launch_bounds__(256, 4) void k_fused(
    const float* __restrict__ x,  const float* __restrict__ W1,
    const float* __restrict__ b1, const float* __restrict__ W2,
    const float* __restrict__ b2, float* __restrict__ v,
    float* __restrict__ c,        float* __restrict__ y,
    float4* __restrict__ out4)
{
    cg::grid_group grid = cg::this_grid();
    const int tid  = blockIdx.x * 256 + threadIdx.x;  // 0 .. 262143
    const int g    = tid >> 6;                        // global wave id, 0..4095
    const int lane = tid & 63;

    // ---- Phase A: one wave per row of W1 (+1 wave for b1) ----
    if (g <= NUM_ATTR) {
        const float* src = (g < NUM_ATTR) ? (W1 + (size_t)g * HID) : b1;
        const float4* s4 = (const float4*)src;   // HID = 500 = 125 float4
        const float4* w4 = (const float4*)W2;
        float acc = 0.f;
        #pragma unroll
        for (int j = lane; j < 125; j += 64) {
            float4 a = s4[j], w = w4[j];
            acc += a.x * w.x + a.y * w.y + a.z * w.z + a.w * w.w;
        }
        #pragma unroll
        for (int off = 32; off >= 1; off >>= 1) acc += __shfl_down(acc, off, 64);
        if (lane == 0) {
            if (g < NUM_ATTR) v[g] = acc;
            else              *c   = acc + b2[0];
        }
    }

    grid.sync();

    // ---- Phase B: one wave per day ----
    if (g < NUM_Y) {
        const float4* xr = (const float4*)(x + (size_t)g * NUM_ATTR);
        const float4* vr = (const float4*)v;
        float4 a0 = xr[lane];
        float4 a1 = xr[lane + 64];
        float4 v0 = vr[lane];
        float4 v1 = vr[lane + 64];
        float acc = a0.x * v0.x + a0.y * v0.y + a0.z * v0.z + a0.w * v0.w
                  + a1.x * v1.x + a1.y * v1.y + a1.z * v1.z + a1.w * v1.w;
        #pragma unroll
        for (int off = 32; off >= 1; off >>= 1) acc += __shfl_xor(acc, off, 64);
        if (lane == 0) y[g] = acc + *c;
    }

    grid.sync();

    // ---- Phase C: one float4 of out per thread (126976 float4s) ----
    if (tid < OUT_ELEMS / 4) {
        const int w    = tid >> 5;        // output row, 0..3967
        const int l    = tid & 31;        // float4 index within row
        const int base = w + (l << 2);
        float4 r;
        r.x = y[base + 0];
        r.y = y[base + 1];
        r.z = y[base + 2];
        r.w = y[base + 3];
        out4[tid] = r;
    }
}

extern "C" void kernel_launch(void* const* d_in, const int* in_sizes, int n_in,
                              void* d_out, int out_size, void* d_ws, size_t ws_size,
                              hipStream_t stream) {
    const float* x  = (const float*)d_in[0];  // [4096, 512]
    const float* W1 = (const float*)d_in[1];  // [512, 500]
    const float* b1 = (const float*)d_in[2];  // [500]
    const float* W2 = (const float*)d_in[3];  // [500, 1]
    const float* b2 = (const float*)d_in[4];  // [1]
    float4* out = (float4*)d_out;             // [507904] floats

    float* ws = (float*)d_ws;
    float* v  = ws;          // 512 floats
    float* c  = ws + 512;    // 1 float
    float* y  = ws + 576;    // 4095 floats

    void* args[] = { (void*)&x, (void*)&W1, (void*)&b1, (void*)&W2, (void*)&b2,
                     (void*)&v, (void*)&c,  (void*)&y,  (void*)&out };
    hipLaunchCooperativeKernel((const void*)k_fused,
                               dim3(1024), dim3(256), args, 0, stream);
}

// Round 3
// 86.577 us; speedup vs baseline: 2.7435x; 2.7435x over previous
//
#include <hip/hip_runtime.h>

// Problem constants (from reference)
#define NUM_DAYS    4096
#define NUM_ATTR    512
#define MB_WIN      128
#define HID         500
#define NUM_BATCHES (NUM_DAYS - MB_WIN)        // 3968
#define NUM_Y       (NUM_BATCHES + MB_WIN - 1) // 4095 distinct day indices
#define OUT_ELEMS   (NUM_BATCHES * MB_WIN)     // 507904

#define ROWS_PER_BLK 16                        // output rows per block
#define DOTS_PER_BLK (ROWS_PER_BLK + MB_WIN - 1)  // 143 y-values needed

// ---------------------------------------------------------------------------
// Kernel 1: fold the MLP:  v[a] = sum_h W1[a,h]*W2[h],  c = b1.W2 + b2
// One wave per output row; float4 lane-strided row reads. Tiny (~1 MB read).
// ---------------------------------------------------------------------------
__global__ __launch_bounds__(64) void k_fold_weights(
    const float* __restrict__ W1, const float* __restrict__ b1,
    const float* __restrict__ W2, const float* __restrict__ b2,
    float* __restrict__ v, float* __restrict__ c) {
    const int b    = blockIdx.x;
    const int lane = threadIdx.x;  // 0..63
    const float* src = (b < NUM_ATTR) ? (W1 + (size_t)b * HID) : b1;
    float acc = 0.f;
    // HID = 500 = 125 float4
    const float4* s4 = (const float4*)src;
    const float4* w4 = (const float4*)W2;
    #pragma unroll
    for (int j = lane; j < 125; j += 64) {
        float4 a = s4[j], w = w4[j];
        acc += a.x * w.x + a.y * w.y + a.z * w.z + a.w * w.w;
    }
    #pragma unroll
    for (int off = 32; off >= 1; off >>= 1) acc += __shfl_down(acc, off, 64);
    if (lane == 0) {
        if (b < NUM_ATTR) v[b] = acc;
        else              *c   = acc + b2[0];
    }
}

// ---------------------------------------------------------------------------
// Kernel 2: block b owns output rows w0 = b*16 .. w0+15.
//   Phase 1: the block's 4 waves compute y[w0 .. w0+142] (143 wave-dots of
//            x rows against register-resident v) into LDS. x rows overlap
//            ~9x between blocks but x (8.4 MB) is L2/L3-resident.
//   Phase 2: write 16 rows (each = y_s[r .. r+127]) as coalesced float4.
// No grid barrier, no y round-trip, one fewer launch than round 1.
// ---------------------------------------------------------------------------
__global__ __launch_bounds__(256) void k_out(
    const float* __restrict__ x, const float* __restrict__ v,
    const float* __restrict__ c, float4* __restrict__ out4) {
    __shared__ float y_s[DOTS_PER_BLK];

    const int wv   = threadIdx.x >> 6;   // wave in block, 0..3
    const int lane = threadIdx.x & 63;
    const int w0   = blockIdx.x * ROWS_PER_BLK;   // first output row

    // v -> registers (2 float4 per lane, L2-hit after first block)
    const float4* vr = (const float4*)v;
    const float4  v0 = vr[lane];
    const float4  v1 = vr[lane + 64];
    const float   cc = *c;

    // Phase 1: wave-strided dots
    for (int i = wv; i < DOTS_PER_BLK; i += 4) {
        const int d = w0 + i;                     // day index, <= 4094
        const float4* xr = (const float4*)(x + (size_t)d * NUM_ATTR);
        float4 a0 = xr[lane];
        float4 a1 = xr[lane + 64];
        float acc = a0.x * v0.x + a0.y * v0.y + a0.z * v0.z + a0.w * v0.w
                  + a1.x * v1.x + a1.y * v1.y + a1.z * v1.z + a1.w * v1.w;
        #pragma unroll
        for (int off = 32; off >= 1; off >>= 1) acc += __shfl_xor(acc, off, 64);
        if (lane == 0) y_s[i] = acc + cc;
    }

    __syncthreads();

    // Phase 2: 16 rows x 32 float4 = 512 float4, 2 per thread
    const int base4 = w0 * (MB_WIN / 4);          // first float4 of row w0
    #pragma unroll
    for (int k = 0; k < 2; ++k) {
        const int t = threadIdx.x + k * 256;      // 0..511
        const int r = t >> 5;                     // row within block, 0..15
        const int l = t & 31;                     // float4 within row
        const int s = r + (l << 2);
        float4 o;
        o.x = y_s[s + 0];
        o.y = y_s[s + 1];
        o.z = y_s[s + 2];
        o.w = y_s[s + 3];
        out4[base4 + t] = o;
    }
}

extern "C" void kernel_launch(void* const* d_in, const int* in_sizes, int n_in,
                              void* d_out, int out_size, void* d_ws, size_t ws_size,
                              hipStream_t stream) {
    const float* x  = (const float*)d_in[0];  // [4096, 512]
    const float* W1 = (const float*)d_in[1];  // [512, 500]
    const float* b1 = (const float*)d_in[2];  // [500]
    const float* W2 = (const float*)d_in[3];  // [500, 1]
    const float* b2 = (const float*)d_in[4];  // [1]
    float4* out = (float4*)d_out;             // [507904] floats

    float* ws = (float*)d_ws;
    float* v  = ws;          // 512 floats
    float* c  = ws + 512;    // 1 float

    k_fold_weights<<<NUM_ATTR + 1, 64, 0, stream>>>(W1, b1, W2, b2, v, c);
    k_out<<<NUM_BATCHES / ROWS_PER_BLK, 256, 0, stream>>>(x, v, c, out);
}

// Round 4
// 69.268 us; speedup vs baseline: 3.4291x; 1.2499x over previous
//
#include <hip/hip_runtime.h>

// Problem constants (from reference)
#define NUM_DAYS    4096
#define NUM_ATTR    512
#define MB_WIN      128
#define HID         500
#define NUM_BATCHES (NUM_DAYS - MB_WIN)        // 3968
#define NUM_Y       (NUM_BATCHES + MB_WIN - 1) // 4095 distinct day indices
#define OUT_ELEMS   (NUM_BATCHES * MB_WIN)     // 507904

// ---------------------------------------------------------------------------
// Kernel 1: fold the MLP:  v[a] = sum_h W1[a,h]*W2[h],  c = b1.W2 + b2
// 256-thread blocks (4 waves) -> 129 blocks, 8 waves/CU during the cold HBM
// read of W1 (was 2 waves/CU with 64-thread blocks) for latency hiding.
// Wave handles one row: lanes split 125 float4 (lane and lane+64).
// ---------------------------------------------------------------------------
__global__ __launch_bounds__(256) void k_fold_weights(
    const float* __restrict__ W1, const float* __restrict__ b1,
    const float* __restrict__ W2, const float* __restrict__ b2,
    float* __restrict__ v, float* __restrict__ c) {
    const int wv   = threadIdx.x >> 6;        // wave in block, 0..3
    const int lane = threadIdx.x & 63;        // 0..63
    const int r    = blockIdx.x * 4 + wv;     // row id, 0..515
    if (r > NUM_ATTR) return;                 // 512 rows + 1 bias wave

    const float* src = (r < NUM_ATTR) ? (W1 + (size_t)r * HID) : b1;
    const float4* s4 = (const float4*)src;    // HID = 500 = 125 float4
    const float4* w4 = (const float4*)W2;
    float acc = 0.f;
    // lane covers j = lane and j = lane+64 (latter only for lane < 61)
    {
        float4 a = s4[lane], w = w4[lane];
        acc += a.x * w.x + a.y * w.y + a.z * w.z + a.w * w.w;
    }
    if (lane < 61) {
        float4 a = s4[lane + 64], w = w4[lane + 64];
        acc += a.x * w.x + a.y * w.y + a.z * w.z + a.w * w.w;
    }
    #pragma unroll
    for (int off = 32; off >= 1; off >>= 1) acc += __shfl_down(acc, off, 64);
    if (lane == 0) {
        if (r < NUM_ATTR) v[r] = acc;
        else              *c   = acc + b2[0];
    }
}

// ---------------------------------------------------------------------------
// Kernel 2: y[d] = x[d,:].v + c  for d in [0, NUM_Y).  One wave per day,
// 4 waves per block -> 1024 blocks = 4 blocks/CU = 4 waves/SIMD.
// Coalesced float4 reads of x (single HBM latency round, a0/a1 independent).
// ---------------------------------------------------------------------------
__global__ __launch_bounds__(256) void k_dot(
    const float* __restrict__ x, const float* __restrict__ v,
    const float* __restrict__ c, float* __restrict__ y) {
    const int wv   = threadIdx.x >> 6;   // wave in block, 0..3
    const int lane = threadIdx.x & 63;   // 0..63
    const int d    = (blockIdx.x << 2) | wv;
    if (d >= NUM_Y) return;

    const float4* xr = (const float4*)(x + (size_t)d * NUM_ATTR);
    const float4* vr = (const float4*)v;
    float4 a0 = xr[lane];
    float4 a1 = xr[lane + 64];
    float4 v0 = vr[lane];
    float4 v1 = vr[lane + 64];
    float acc = a0.x * v0.x + a0.y * v0.y + a0.z * v0.z + a0.w * v0.w
              + a1.x * v1.x + a1.y * v1.y + a1.z * v1.z + a1.w * v1.w;
    #pragma unroll
    for (int off = 32; off >= 1; off >>= 1) acc += __shfl_xor(acc, off, 64);
    if (lane == 0) y[d] = acc + *c;
}

// ---------------------------------------------------------------------------
// Kernel 3: replicate.  out row w (128 floats) == y[w .. w+127], contiguous.
// One float4 of out per thread: 4 scalar reads of the 16 KB L1/L2-resident y,
// one fully-coalesced 16 B store.  126976 threads = 496 blocks x 256.
// ---------------------------------------------------------------------------
__global__ __launch_bounds__(256) void k_replicate(
    const float* __restrict__ y, float4* __restrict__ out4) {
    const int t = blockIdx.x * 256 + threadIdx.x;  // 0 .. 126975
    const int w = t >> 5;        // output row, 0..3967
    const int l = t & 31;        // float4 index within row
    const int base = w + (l << 2);
    float4 r;
    r.x = y[base + 0];
    r.y = y[base + 1];
    r.z = y[base + 2];
    r.w = y[base + 3];
    out4[t] = r;
}

extern "C" void kernel_launch(void* const* d_in, const int* in_sizes, int n_in,
                              void* d_out, int out_size, void* d_ws, size_t ws_size,
                              hipStream_t stream) {
    const float* x  = (const float*)d_in[0];  // [4096, 512]
    const float* W1 = (const float*)d_in[1];  // [512, 500]
    const float* b1 = (const float*)d_in[2];  // [500]
    const float* W2 = (const float*)d_in[3];  // [500, 1]
    const float* b2 = (const float*)d_in[4];  // [1]
    float* out = (float*)d_out;               // [507904]

    float* ws = (float*)d_ws;
    float* v  = ws;          // 512 floats
    float* c  = ws + 512;    // 1 float
    float* y  = ws + 576;    // 4095 floats

    k_fold_weights<<<(NUM_ATTR + 1 + 3) / 4, 256, 0, stream>>>(W1, b1, W2, b2, v, c);
    k_dot<<<(NUM_Y + 3) / 4, 256, 0, stream>>>(x, v, c, y);
    k_replicate<<<(OUT_ELEMS / 4) / 256, 256, 0, stream>>>(y, (float4*)out);
}